// Round 6
// baseline (150.680 us; speedup 1.0000x reference)
//
#include <hip/hip_runtime.h>
#include <stdint.h>

#define NN 4096
#define MM 8192
#define DD 512
#define KT 8  // 512 / BK, BK = 64

typedef __bf16 bf16x8 __attribute__((ext_vector_type(8)));
typedef __bf16 bf16x4 __attribute__((ext_vector_type(4)));
typedef float f32x4 __attribute__((ext_vector_type(4)));
typedef float f32x16 __attribute__((ext_vector_type(16)));

__device__ __forceinline__ void load_lds16(const void* g, void* l) {
  // async global -> LDS, 16B/lane; LDS dest must be wave-uniform base + lane*16.
  __builtin_amdgcn_global_load_lds(
      (const __attribute__((address_space(1))) unsigned int*)g,
      (__attribute__((address_space(3))) unsigned int*)l, 16, 0, 0);
}

// VALU-pipe partial reduction (R7/R8-verified correct): x += rot16(x, k).
template <int CTRL>
__device__ __forceinline__ float dpp_radd(float x) {
  int xi = __float_as_int(x);
  int mv = __builtin_amdgcn_update_dpp(xi, xi, CTRL, 0xF, 0xF, false);
  return x + __int_as_float(mv);
}
__device__ __forceinline__ float swz_add_xor16(float x) {
  int sv = __builtin_amdgcn_ds_swizzle(__float_as_int(x), 0x401F);
  return x + __int_as_float(sv);
}

// 4 rows per 256-thread block, one wave per row. R0 verbatim (verified).
__global__ __launch_bounds__(256) void convert_norm_kernel(
    const float* __restrict__ X, const float* __restrict__ SV,
    __bf16* __restrict__ Xb, __bf16* __restrict__ SVb,
    float* __restrict__ x2, float* __restrict__ sv2,
    float* __restrict__ out, const float* __restrict__ IC) {
  int wid = blockIdx.x * 4 + (threadIdx.x >> 6);
  int lane = threadIdx.x & 63;
  const float* src;
  __bf16* dst;
  float* nrm;
  if (wid < NN) {
    src = X + (size_t)wid * DD;
    dst = Xb + (size_t)wid * DD;
    nrm = x2 + wid;
    if (lane == 0) out[wid] = IC[0];
  } else {
    int r = wid - NN;
    src = SV + (size_t)r * DD;
    dst = SVb + (size_t)r * DD;
    nrm = sv2 + r;
  }
  const f32x4* s = (const f32x4*)src;
  f32x4 a = s[lane];       // elements 4l..4l+3
  f32x4 b = s[lane + 64];  // elements 256+4l..
  float sum = a.x * a.x + a.y * a.y + a.z * a.z + a.w * a.w +
              b.x * b.x + b.y * b.y + b.z * b.z + b.w * b.w;
  bf16x4 ca = {(__bf16)a.x, (__bf16)a.y, (__bf16)a.z, (__bf16)a.w};
  bf16x4 cb = {(__bf16)b.x, (__bf16)b.y, (__bf16)b.z, (__bf16)b.w};
  *(bf16x4*)(dst + 4 * lane) = ca;
  *(bf16x4*)(dst + 256 + 4 * lane) = cb;
#pragma unroll
  for (int m = 32; m >= 1; m >>= 1) sum += __shfl_xor(sum, m, 64);
  if (lane == 0) *nrm = sum;
}

// 128x256 tile, BK=64, 4 waves (2n x 2m), each wave 64x128 via 2x4 of
// mfma_32x32x16 (acc = 128 AGPR). Both operands through the proven
// global_load_lds -> XOR-swizzled LDS -> ds_read_b128 path (R4/R5 showed
// direct-VMEM operand reads regress). Per wave-kt: 24 ds_read / 32 MFMA
// (0.75:1 vs champion's 1:1), staging instrs/MFMA -25%, barriers/FLOP
// halved. LDS 48 KB -> 3 blocks/CU (12 waves). XOR algebra identical to
// champion (row bases are multiples of 32). Epilogue = R5's thinned form
// (verified exact-equivalent). XCD chunk: 2x4 chunks of 16n x 8m tiles
// -> 2 MB A + 2 MB B per XCD L2.
__global__ __launch_bounds__(256, 3) void rbf_gemm_kernel(
    const bf16x8* __restrict__ Xb, const bf16x8* __restrict__ SVb,
    const float* __restrict__ x2, const float* __restrict__ sv2,
    const float* __restrict__ DC, const float* __restrict__ gamma_p,
    float* __restrict__ out) {
  __shared__ bf16x8 As[1024];  // 16 KB: 128 rows x 8 granules
  __shared__ bf16x8 Bs[2048];  // 32 KB: 256 rows x 8 granules

  const int t = threadIdx.x;
  const int lane = t & 63;
  const int wave = t >> 6;

  // ---- XCD-chunked bijective swizzle (grid 32x32) ----
  const int id = blockIdx.y * gridDim.x + blockIdx.x;
  const int xcd = id & 7;
  const int idx = id >> 3;  // 0..127
  const int bn = (xcd & 1) * 16 + (idx & 15);
  const int bm = (xcd >> 1) * 8 + (idx >> 4);
  const int n0 = bn * 128;
  const int m0 = bm * 256;

  const int wave_n = wave & 1;   // 2 waves in n -> 64 rows each
  const int wave_m = wave >> 1;  // 2 waves in m -> 128 cols each
  const int l31 = lane & 31;
  const int lhi = lane >> 5;

  // staging decomposition: chunk c = it*256 + t; row = c>>3; slot = c&7
  const int srow = t >> 3;
  const int sslot = t & 7;

  f32x16 acc[2][4];
#pragma unroll
  for (int i = 0; i < 2; ++i)
#pragma unroll
    for (int j = 0; j < 4; ++j)
#pragma unroll
      for (int r = 0; r < 16; ++r) acc[i][j][r] = 0.0f;

  for (int kt = 0; kt < KT; ++kt) {
    // ---- cooperative staging: 4 instrs A + 8 instrs B per thread ----
#pragma unroll
    for (int it = 0; it < 4; ++it) {
      const int c = it * 256 + t;
      const int row = it * 32 + srow;
      const int kg = sslot ^ (row & 7);
      load_lds16(Xb + (size_t)(n0 + row) * 64 + kt * 8 + kg, &As[c]);
    }
#pragma unroll
    for (int it = 0; it < 8; ++it) {
      const int c = it * 256 + t;
      const int row = it * 32 + srow;
      const int kg = sslot ^ (row & 7);
      load_lds16(SVb + (size_t)(m0 + row) * 64 + kt * 8 + kg, &Bs[c]);
    }
    __syncthreads();
    // ---- compute: per ks, 6 ds_read_b128 + 8 MFMA ----
    const int ra = (wave_n * 64 + l31) * 8;
    const int rb = (wave_m * 128 + l31) * 8;
#pragma unroll
    for (int ks = 0; ks < 4; ++ks) {
      const int sw = (ks * 2 + lhi) ^ (l31 & 7);
      bf16x8 af0 = As[ra + sw];
      bf16x8 af1 = As[ra + 256 + sw];  // +32 rows
      bf16x8 bf0 = Bs[rb + sw];
      bf16x8 bf1 = Bs[rb + 256 + sw];
      bf16x8 bf2 = Bs[rb + 512 + sw];
      bf16x8 bf3 = Bs[rb + 768 + sw];
      acc[0][0] = __builtin_amdgcn_mfma_f32_32x32x16_bf16(af0, bf0, acc[0][0], 0, 0, 0);
      acc[0][1] = __builtin_amdgcn_mfma_f32_32x32x16_bf16(af0, bf1, acc[0][1], 0, 0, 0);
      acc[0][2] = __builtin_amdgcn_mfma_f32_32x32x16_bf16(af0, bf2, acc[0][2], 0, 0, 0);
      acc[0][3] = __builtin_amdgcn_mfma_f32_32x32x16_bf16(af0, bf3, acc[0][3], 0, 0, 0);
      acc[1][0] = __builtin_amdgcn_mfma_f32_32x32x16_bf16(af1, bf0, acc[1][0], 0, 0, 0);
      acc[1][1] = __builtin_amdgcn_mfma_f32_32x32x16_bf16(af1, bf1, acc[1][1], 0, 0, 0);
      acc[1][2] = __builtin_amdgcn_mfma_f32_32x32x16_bf16(af1, bf2, acc[1][2], 0, 0, 0);
      acc[1][3] = __builtin_amdgcn_mfma_f32_32x32x16_bf16(af1, bf3, acc[1][3], 0, 0, 0);
    }
    __syncthreads();
  }

  // ---- epilogue (R5-verified thinned math; widened to 4 m-groups) ----
  const float g = gamma_p[0];
  const float c2 = g * 1.4426950408889634f;  // gamma * log2(e)
  const float t2 = 2.0f * c2;

  float sv2v[4], dcv[4], nsv[4];
  const int colb = m0 + wave_m * 128 + l31;
#pragma unroll
  for (int j = 0; j < 4; ++j) {
    sv2v[j] = sv2[colb + 32 * j];
    dcv[j] = DC[colb + 32 * j];
    nsv[j] = -c2 * sv2v[j];
  }

#pragma unroll
  for (int i = 0; i < 2; ++i) {
    // C row = rowb + 8*g4 + r2, where reg = g4*4 + r2
    const int rowb = n0 + wave_n * 64 + i * 32 + 4 * lhi;
    float val[16];
#pragma unroll
    for (int g4 = 0; g4 < 4; ++g4) {
      f32x4 xv = *(const f32x4*)(x2 + rowb + 8 * g4);
#pragma unroll
      for (int r2 = 0; r2 < 4; ++r2) {
        const int reg = g4 * 4 + r2;
        float v = 0.0f;
#pragma unroll
        for (int j = 0; j < 4; ++j) {
          float e = fmaf(t2, acc[i][j][reg], fmaf(-c2, xv[r2], nsv[j]));
          e = fminf(e, 0.0f);  // == -c2 * max(d2, 0)
          v = fmaf(exp2f(e), dcv[j], v);
        }
        val[reg] = v;
      }
    }
    // reduce over 32 column-lanes: 4 DPP row-rotations (VALU pipe) + one
    // ds_swizzle xor16 (R7/R8-verified).
#pragma unroll
    for (int reg = 0; reg < 16; ++reg) {
      float v = val[reg];
      v = dpp_radd<0x121>(v);  // row_ror:1
      v = dpp_radd<0x122>(v);  // row_ror:2
      v = dpp_radd<0x124>(v);  // row_ror:4
      v = dpp_radd<0x128>(v);  // row_ror:8
      val[reg] = swz_add_xor16(v);
    }
    if (l31 == 0) {
#pragma unroll
      for (int g4 = 0; g4 < 4; ++g4)
#pragma unroll
        for (int r2 = 0; r2 < 4; ++r2)
          atomicAdd(&out[rowb + 8 * g4 + r2], val[g4 * 4 + r2]);
    }
  }
}

extern "C" void kernel_launch(void* const* d_in, const int* in_sizes, int n_in,
                              void* d_out, int out_size, void* d_ws, size_t ws_size,
                              hipStream_t stream) {
  const float* X = (const float*)d_in[0];
  const float* SV = (const float*)d_in[1];
  const float* DC = (const float*)d_in[2];
  const float* IC = (const float*)d_in[3];
  const float* gamma = (const float*)d_in[4];
  float* out = (float*)d_out;

  char* ws = (char*)d_ws;
  __bf16* Xb = (__bf16*)ws;                                   // 4 MB
  __bf16* SVb = (__bf16*)(ws + (size_t)NN * DD * 2);          // 8 MB
  float* x2 = (float*)(ws + (size_t)(NN + MM) * DD * 2);      // 16 KB
  float* sv2 = x2 + NN;                                       // 32 KB

  convert_norm_kernel<<<(NN + MM) / 4, 256, 0, stream>>>(X, SV, Xb, SVb, x2, sv2, out, IC);
  dim3 grid(NN / 128, MM / 256);
  rbf_gemm_kernel<<<grid, 256, 0, stream>>>((const bf16x8*)Xb, (const bf16x8*)SVb,
                                            x2, sv2, DC, gamma, out);
}

// Round 7
// 135.106 us; speedup vs baseline: 1.1153x; 1.1153x over previous
//
#include <hip/hip_runtime.h>
#include <stdint.h>

#define NN 4096
#define MM 8192
#define DD 512

typedef __bf16 bf16x8 __attribute__((ext_vector_type(8)));
typedef __bf16 bf16x4 __attribute__((ext_vector_type(4)));
typedef float f32x4 __attribute__((ext_vector_type(4)));
typedef float f32x16 __attribute__((ext_vector_type(16)));

__device__ __forceinline__ void load_lds16(const void* g, void* l) {
  // async global -> LDS, 16B/lane; LDS dest must be wave-uniform base + lane*16.
  __builtin_amdgcn_global_load_lds(
      (const __attribute__((address_space(1))) unsigned int*)g,
      (__attribute__((address_space(3))) unsigned int*)l, 16, 0, 0);
}

// VALU-pipe partial reduction (R7/R8-verified correct): x += rot16(x, k).
template <int CTRL>
__device__ __forceinline__ float dpp_radd(float x) {
  int xi = __float_as_int(x);
  int mv = __builtin_amdgcn_update_dpp(xi, xi, CTRL, 0xF, 0xF, false);
  return x + __int_as_float(mv);
}
__device__ __forceinline__ float swz_add_xor16(float x) {
  int sv = __builtin_amdgcn_ds_swizzle(__float_as_int(x), 0x401F);
  return x + __int_as_float(sv);
}

// 4 rows per 256-thread block, one wave per row. R0 verbatim (verified).
__global__ __launch_bounds__(256) void convert_norm_kernel(
    const float* __restrict__ X, const float* __restrict__ SV,
    __bf16* __restrict__ Xb, __bf16* __restrict__ SVb,
    float* __restrict__ x2, float* __restrict__ sv2,
    float* __restrict__ out, const float* __restrict__ IC) {
  int wid = blockIdx.x * 4 + (threadIdx.x >> 6);
  int lane = threadIdx.x & 63;
  const float* src;
  __bf16* dst;
  float* nrm;
  if (wid < NN) {
    src = X + (size_t)wid * DD;
    dst = Xb + (size_t)wid * DD;
    nrm = x2 + wid;
    if (lane == 0) out[wid] = IC[0];
  } else {
    int r = wid - NN;
    src = SV + (size_t)r * DD;
    dst = SVb + (size_t)r * DD;
    nrm = sv2 + r;
  }
  const f32x4* s = (const f32x4*)src;
  f32x4 a = s[lane];       // elements 4l..4l+3
  f32x4 b = s[lane + 64];  // elements 256+4l..
  float sum = a.x * a.x + a.y * a.y + a.z * a.z + a.w * a.w +
              b.x * b.x + b.y * b.y + b.z * b.z + b.w * b.w;
  bf16x4 ca = {(__bf16)a.x, (__bf16)a.y, (__bf16)a.z, (__bf16)a.w};
  bf16x4 cb = {(__bf16)b.x, (__bf16)b.y, (__bf16)b.z, (__bf16)b.w};
  *(bf16x4*)(dst + 4 * lane) = ca;
  *(bf16x4*)(dst + 256 + 4 * lane) = cb;
#pragma unroll
  for (int m = 32; m >= 1; m >>= 1) sum += __shfl_xor(sum, m, 64);
  if (lane == 0) *nrm = sum;
}

// Champion chassis (128x128, 4 waves 2x2, 32 KB LDS -> 4 blocks/CU, XCD
// swizzle) with ONE structural change: BK=32 double-buffer so the stage of
// step h+1 is issued BEFORE compute of step h, and the per-step
// __syncthreads' vmcnt(0) drain is covered by the step's own ds_read+MFMA
// (champion drained ~10 instrs after issue: pure idle, only cross-block TLP
// covered it -> measured 60% issue-idle). Ring invariants: buf[(h+1)&1] was
// last read in step h-1 (sealed by that sync); stage(h) drained by step
// h-1's sync. Barrier count unchanged (16). Swizzle for 4-granule rows:
// kg = slot ^ (row&3) ^ ((row>>3)&3) — bank-checked at the b128 floor
// (4 lanes/bank-quad); read side uses the same XOR (row bases = 0 mod 32).
// Epilogue = R5's thinned form (verified twice); convert/XCD map unchanged.
__global__ __launch_bounds__(256, 4) void rbf_gemm_kernel(
    const bf16x8* __restrict__ Xb, const bf16x8* __restrict__ SVb,
    const float* __restrict__ x2, const float* __restrict__ sv2,
    const float* __restrict__ DC, const float* __restrict__ gamma_p,
    float* __restrict__ out) {
  __shared__ bf16x8 As[1024];  // [2][512]: 2 bufs x (128 rows x 4 granules), 16 KB
  __shared__ bf16x8 Bs[1024];  // 16 KB

  const int t = threadIdx.x;
  const int lane = t & 63;
  const int wave = t >> 6;

  // ---- XCD-chunked bijective swizzle (R3-verified: FETCH 35->16.6 MB) ----
  const int id = blockIdx.y * gridDim.x + blockIdx.x;
  const int xcd = id & 7;
  const int idx = id >> 3;
  const int bn = (xcd & 1) * 16 + (idx & 15);
  const int bm = (xcd >> 1) * 16 + (idx >> 4);
  const int n0 = bn * 128;
  const int m0 = bm * 128;

  const int wave_m = wave & 1;   // m-dir of C
  const int wave_n = wave >> 1;  // n-dir of C
  const int l31 = lane & 31;
  const int lhi = lane >> 5;

  // staging decomposition: half-tile = 512 granules; thread t handles
  // granules c = t and c = 256+t. row = c>>2 (it=1 -> +64 rows), slot = c&3.
  // kg identical for both (row+64 preserves row&3 and (row>>3)&3).
  const int srow = t >> 2;
  const int sslot = t & 3;
  const int kg = sslot ^ (srow & 3) ^ ((srow >> 3) & 3);
  const bf16x8* gA0 = Xb + (size_t)(n0 + srow) * 64 + kg;
  const bf16x8* gA1 = Xb + (size_t)(n0 + srow + 64) * 64 + kg;
  const bf16x8* gB0 = SVb + (size_t)(m0 + srow) * 64 + kg;
  const bf16x8* gB1 = SVb + (size_t)(m0 + srow + 64) * 64 + kg;

  // fragment-read bases (granule units; 4 granules/row)
  const int ra = (wave_n * 64 + l31) * 4;
  const int rb = (wave_m * 64 + l31) * 4;
  const int xsw = (l31 & 3) ^ ((l31 >> 3) & 3);

  f32x16 acc[2][2];
#pragma unroll
  for (int i = 0; i < 2; ++i)
#pragma unroll
    for (int j = 0; j < 2; ++j)
#pragma unroll
      for (int r = 0; r < 16; ++r) acc[i][j][r] = 0.0f;

  // stage step h (BK=32 slab h) into buffer p
  auto stage = [&](int h, int p) {
    const int o = h * 4;
    const int d = p * 512 + t;
    load_lds16(gA0 + o, &As[d]);
    load_lds16(gA1 + o, &As[d + 256]);
    load_lds16(gB0 + o, &Bs[d]);
    load_lds16(gB1 + o, &Bs[d + 256]);
  };
  // compute step h from buffer p: 8 ds_read_b128 + 8 MFMA
  auto compute = [&](int p) {
    const bf16x8* Ab = As + p * 512;
    const bf16x8* Bb = Bs + p * 512;
#pragma unroll
    for (int ks = 0; ks < 2; ++ks) {
      const int sw = (ks * 2 + lhi) ^ xsw;
      bf16x8 af0 = Ab[ra + sw];
      bf16x8 af1 = Ab[ra + 128 + sw];  // +32 rows
      bf16x8 bf0 = Bb[rb + sw];
      bf16x8 bf1 = Bb[rb + 128 + sw];
      acc[0][0] = __builtin_amdgcn_mfma_f32_32x32x16_bf16(af0, bf0, acc[0][0], 0, 0, 0);
      acc[0][1] = __builtin_amdgcn_mfma_f32_32x32x16_bf16(af0, bf1, acc[0][1], 0, 0, 0);
      acc[1][0] = __builtin_amdgcn_mfma_f32_32x32x16_bf16(af1, bf0, acc[1][0], 0, 0, 0);
      acc[1][1] = __builtin_amdgcn_mfma_f32_32x32x16_bf16(af1, bf1, acc[1][1], 0, 0, 0);
    }
  };

  // prologue: stage slab 0 (only uncovered drain in the kernel)
  stage(0, 0);
  __syncthreads();

  for (int h = 0; h < 15; ++h) {
    stage(h + 1, (h + 1) & 1);  // issue next slab FIRST (latency covered below)
    compute(h & 1);
    __syncthreads();            // vmcnt(0)+lgkmcnt(0)+barrier: drain now covered
  }
  compute(1);  // slab 15, no further staging

  // ---- epilogue (R5-verified thinned math; no barriers) ----
  const float g = gamma_p[0];
  const float c2 = g * 1.4426950408889634f;  // gamma * log2(e)
  const float t2 = 2.0f * c2;

  float sv2v[2], dcv[2], nsv[2];
  const int colb = m0 + wave_m * 64 + l31;
  sv2v[0] = sv2[colb];
  dcv[0] = DC[colb];
  sv2v[1] = sv2[colb + 32];
  dcv[1] = DC[colb + 32];
  nsv[0] = -c2 * sv2v[0];
  nsv[1] = -c2 * sv2v[1];

#pragma unroll
  for (int i = 0; i < 2; ++i) {
    // C row = rowb + 8*g4 + r2, where reg = g4*4 + r2
    const int rowb = n0 + wave_n * 64 + i * 32 + 4 * lhi;
    float val[16];
#pragma unroll
    for (int g4 = 0; g4 < 4; ++g4) {
      f32x4 xv = *(const f32x4*)(x2 + rowb + 8 * g4);
#pragma unroll
      for (int r2 = 0; r2 < 4; ++r2) {
        const int reg = g4 * 4 + r2;
        float v = 0.0f;
#pragma unroll
        for (int j = 0; j < 2; ++j) {
          float e = fmaf(t2, acc[i][j][reg], fmaf(-c2, xv[r2], nsv[j]));
          e = fminf(e, 0.0f);  // == -c2 * max(d2, 0)
          v = fmaf(exp2f(e), dcv[j], v);
        }
        val[reg] = v;
      }
    }
    // reduce over 32 column-lanes: 4 DPP row-rotations (VALU pipe) + one
    // ds_swizzle xor16 (R7/R8-verified).
#pragma unroll
    for (int reg = 0; reg < 16; ++reg) {
      float v = val[reg];
      v = dpp_radd<0x121>(v);  // row_ror:1
      v = dpp_radd<0x122>(v);  // row_ror:2
      v = dpp_radd<0x124>(v);  // row_ror:4
      v = dpp_radd<0x128>(v);  // row_ror:8
      val[reg] = swz_add_xor16(v);
    }
    if (l31 == 0) {
#pragma unroll
      for (int g4 = 0; g4 < 4; ++g4)
#pragma unroll
        for (int r2 = 0; r2 < 4; ++r2)
          atomicAdd(&out[rowb + 8 * g4 + r2], val[g4 * 4 + r2]);
    }
  }
}

extern "C" void kernel_launch(void* const* d_in, const int* in_sizes, int n_in,
                              void* d_out, int out_size, void* d_ws, size_t ws_size,
                              hipStream_t stream) {
  const float* X = (const float*)d_in[0];
  const float* SV = (const float*)d_in[1];
  const float* DC = (const float*)d_in[2];
  const float* IC = (const float*)d_in[3];
  const float* gamma = (const float*)d_in[4];
  float* out = (float*)d_out;

  char* ws = (char*)d_ws;
  __bf16* Xb = (__bf16*)ws;                                   // 4 MB
  __bf16* SVb = (__bf16*)(ws + (size_t)NN * DD * 2);          // 8 MB
  float* x2 = (float*)(ws + (size_t)(NN + MM) * DD * 2);      // 16 KB
  float* sv2 = x2 + NN;                                       // 32 KB

  convert_norm_kernel<<<(NN + MM) / 4, 256, 0, stream>>>(X, SV, Xb, SVb, x2, sv2, out, IC);
  dim3 grid(NN / 128, MM / 128);
  rbf_gemm_kernel<<<grid, 256, 0, stream>>>((const bf16x8*)Xb, (const bf16x8*)SVb,
                                            x2, sv2, DC, gamma, out);
}

// Round 8
// 130.249 us; speedup vs baseline: 1.1569x; 1.0373x over previous
//
#include <hip/hip_runtime.h>
#include <stdint.h>

#define NN 4096
#define MM 8192
#define DD 512
#define KT 8  // 512 / BK, BK = 64

typedef __bf16 bf16x8 __attribute__((ext_vector_type(8)));
typedef __bf16 bf16x4 __attribute__((ext_vector_type(4)));
typedef float f32x4 __attribute__((ext_vector_type(4)));
typedef float f32x16 __attribute__((ext_vector_type(16)));

__device__ __forceinline__ void load_lds16(const void* g, void* l) {
  // async global -> LDS, 16B/lane; LDS dest must be wave-uniform base + lane*16.
  __builtin_amdgcn_global_load_lds(
      (const __attribute__((address_space(1))) unsigned int*)g,
      (__attribute__((address_space(3))) unsigned int*)l, 16, 0, 0);
}

// VALU-pipe partial reduction (R7/R8-verified correct): x += rot16(x, k).
template <int CTRL>
__device__ __forceinline__ float dpp_radd(float x) {
  int xi = __float_as_int(x);
  int mv = __builtin_amdgcn_update_dpp(xi, xi, CTRL, 0xF, 0xF, false);
  return x + __int_as_float(mv);
}
__device__ __forceinline__ float swz_add_xor16(float x) {
  int sv = __builtin_amdgcn_ds_swizzle(__float_as_int(x), 0x401F);
  return x + __int_as_float(sv);
}

// 4 rows per 256-thread block, one wave per row. R0 verbatim (verified).
__global__ __launch_bounds__(256) void convert_norm_kernel(
    const float* __restrict__ X, const float* __restrict__ SV,
    __bf16* __restrict__ Xb, __bf16* __restrict__ SVb,
    float* __restrict__ x2, float* __restrict__ sv2,
    float* __restrict__ out, const float* __restrict__ IC) {
  int wid = blockIdx.x * 4 + (threadIdx.x >> 6);
  int lane = threadIdx.x & 63;
  const float* src;
  __bf16* dst;
  float* nrm;
  if (wid < NN) {
    src = X + (size_t)wid * DD;
    dst = Xb + (size_t)wid * DD;
    nrm = x2 + wid;
    if (lane == 0) out[wid] = IC[0];
  } else {
    int r = wid - NN;
    src = SV + (size_t)r * DD;
    dst = SVb + (size_t)r * DD;
    nrm = sv2 + r;
  }
  const f32x4* s = (const f32x4*)src;
  f32x4 a = s[lane];       // elements 4l..4l+3
  f32x4 b = s[lane + 64];  // elements 256+4l..
  float sum = a.x * a.x + a.y * a.y + a.z * a.z + a.w * a.w +
              b.x * b.x + b.y * b.y + b.z * b.z + b.w * b.w;
  bf16x4 ca = {(__bf16)a.x, (__bf16)a.y, (__bf16)a.z, (__bf16)a.w};
  bf16x4 cb = {(__bf16)b.x, (__bf16)b.y, (__bf16)b.z, (__bf16)b.w};
  *(bf16x4*)(dst + 4 * lane) = ca;
  *(bf16x4*)(dst + 256 + 4 * lane) = cb;
#pragma unroll
  for (int m = 32; m >= 1; m >>= 1) sum += __shfl_xor(sum, m, 64);
  if (lane == 0) *nrm = sum;
}

// Champion chassis VERBATIM (128x128, BK=64, 4 waves 2x2, single 32 KB LDS
// buffer -> 4 blocks/CU, 2 syncs/kt, XCD swizzle). ONE variable changed:
// the LDS granule permutation is replaced by R7's measured-ZERO-conflict
// form. Each operand tile is viewed [2 k-halves][128 rows][4 slots]; slot s
// of row r in half h stores global granule h*4 + (s ^ (r&3) ^ ((r>>3)&3));
// the reader fetches granule kc at slot (kc&3) ^ (l31&3) ^ ((l31>>3)&3) in
// half kc>>2 (XORs cancel; +32/+64-row offsets preserve both XOR fields).
// R7 measured SQ_LDS_BANK_CONFLICT == 0 with this exact stage/read pair.
// Epilogue = R5's thinned form (twice harness-verified).
__global__ __launch_bounds__(256, 4) void rbf_gemm_kernel(
    const bf16x8* __restrict__ Xb, const bf16x8* __restrict__ SVb,
    const float* __restrict__ x2, const float* __restrict__ sv2,
    const float* __restrict__ DC, const float* __restrict__ gamma_p,
    float* __restrict__ out) {
  __shared__ bf16x8 As[1024];  // 16 KB: [2 halves][128 rows][4 slots]
  __shared__ bf16x8 Bs[1024];  // 16 KB

  const int t = threadIdx.x;
  const int lane = t & 63;
  const int wave = t >> 6;

  // ---- XCD-chunked bijective swizzle (R3-verified: FETCH 35->16.6 MB) ----
  const int id = blockIdx.y * gridDim.x + blockIdx.x;
  const int xcd = id & 7;
  const int idx = id >> 3;
  const int bn = (xcd & 1) * 16 + (idx & 15);
  const int bm = (xcd >> 1) * 16 + (idx >> 4);
  const int n0 = bn * 128;
  const int m0 = bm * 128;

  const int wave_m = wave & 1;   // m-dir of C
  const int wave_n = wave >> 1;  // n-dir of C
  const int l31 = lane & 31;
  const int lhi = lane >> 5;

  // staging decomposition: flat LDS granule c = it*256 + t;
  // half = c>>9, row = (c>>2)&127, slot = c&3.
  // global granule for (half,row,slot): half*4 + (slot ^ (row&3) ^ ((row>>3)&3))
  const int srow_ = (t >> 2) & 63;        // row bits from t (it adds 64s/halves)
  const int sslot = t & 3;

  // fragment-read bases: within-half granule index (4 granules/row)
  const int ra = (wave_n * 64 + l31) * 4;
  const int rb = (wave_m * 64 + l31) * 4;
  const int xsw = (l31 & 3) ^ ((l31 >> 3) & 3);

  f32x16 acc[2][2];
#pragma unroll
  for (int i = 0; i < 2; ++i)
#pragma unroll
    for (int j = 0; j < 2; ++j)
#pragma unroll
      for (int r = 0; r < 16; ++r) acc[i][j][r] = 0.0f;

  for (int kt = 0; kt < KT; ++kt) {
    // ---- cooperative staging: 4 instrs A + 4 instrs B per thread ----
#pragma unroll
    for (int it = 0; it < 4; ++it) {
      const int c = it * 256 + t;
      const int half = c >> 9;
      const int row = (c >> 2) & 127;
      const int kg = half * 4 + (sslot ^ (row & 3) ^ ((row >> 3) & 3));
      load_lds16(Xb + (size_t)(n0 + row) * 64 + kt * 8 + kg, &As[c]);
      load_lds16(SVb + (size_t)(m0 + row) * 64 + kt * 8 + kg, &Bs[c]);
    }
    __syncthreads();
    // ---- compute (identical order/count to champion) ----
#pragma unroll
    for (int ks = 0; ks < 4; ++ks) {
      const int kc = ks * 2 + lhi;            // k-granule 0..7
      const int h = ks >> 1;                  // half = kc>>2 (lane-uniform)
      const int sw = (kc & 3) ^ xsw;          // slot within half
      const bf16x8* Ah = As + h * 512;
      const bf16x8* Bh = Bs + h * 512;
      bf16x8 af0 = Ah[ra + sw];
      bf16x8 af1 = Ah[ra + 128 + sw];  // +32 rows
      bf16x8 bf0 = Bh[rb + sw];
      bf16x8 bf1 = Bh[rb + 128 + sw];
      acc[0][0] = __builtin_amdgcn_mfma_f32_32x32x16_bf16(af0, bf0, acc[0][0], 0, 0, 0);
      acc[0][1] = __builtin_amdgcn_mfma_f32_32x32x16_bf16(af0, bf1, acc[0][1], 0, 0, 0);
      acc[1][0] = __builtin_amdgcn_mfma_f32_32x32x16_bf16(af1, bf0, acc[1][0], 0, 0, 0);
      acc[1][1] = __builtin_amdgcn_mfma_f32_32x32x16_bf16(af1, bf1, acc[1][1], 0, 0, 0);
    }
    __syncthreads();
  }

  // ---- epilogue (R5-verified thinned math; no barriers) ----
  const float g = gamma_p[0];
  const float c2 = g * 1.4426950408889634f;  // gamma * log2(e)
  const float t2 = 2.0f * c2;

  float sv2v[2], dcv[2], nsv[2];
  const int colb = m0 + wave_m * 64 + l31;
  sv2v[0] = sv2[colb];
  dcv[0] = DC[colb];
  sv2v[1] = sv2[colb + 32];
  dcv[1] = DC[colb + 32];
  nsv[0] = -c2 * sv2v[0];
  nsv[1] = -c2 * sv2v[1];

#pragma unroll
  for (int i = 0; i < 2; ++i) {
    // C row = rowb + 8*g4 + r2, where reg = g4*4 + r2
    const int rowb = n0 + wave_n * 64 + i * 32 + 4 * lhi;
    float val[16];
#pragma unroll
    for (int g4 = 0; g4 < 4; ++g4) {
      f32x4 xv = *(const f32x4*)(x2 + rowb + 8 * g4);
#pragma unroll
      for (int r2 = 0; r2 < 4; ++r2) {
        const int reg = g4 * 4 + r2;
        float v = 0.0f;
#pragma unroll
        for (int j = 0; j < 2; ++j) {
          float e = fmaf(t2, acc[i][j][reg], fmaf(-c2, xv[r2], nsv[j]));
          e = fminf(e, 0.0f);  // == -c2 * max(d2, 0)
          v = fmaf(exp2f(e), dcv[j], v);
        }
        val[reg] = v;
      }
    }
    // reduce over 32 column-lanes: 4 DPP row-rotations (VALU pipe) + one
    // ds_swizzle xor16 (R7/R8-verified).
#pragma unroll
    for (int reg = 0; reg < 16; ++reg) {
      float v = val[reg];
      v = dpp_radd<0x121>(v);  // row_ror:1
      v = dpp_radd<0x122>(v);  // row_ror:2
      v = dpp_radd<0x124>(v);  // row_ror:4
      v = dpp_radd<0x128>(v);  // row_ror:8
      val[reg] = swz_add_xor16(v);
    }
    if (l31 == 0) {
#pragma unroll
      for (int g4 = 0; g4 < 4; ++g4)
#pragma unroll
        for (int r2 = 0; r2 < 4; ++r2)
          atomicAdd(&out[rowb + 8 * g4 + r2], val[g4 * 4 + r2]);
    }
  }
}

extern "C" void kernel_launch(void* const* d_in, const int* in_sizes, int n_in,
                              void* d_out, int out_size, void* d_ws, size_t ws_size,
                              hipStream_t stream) {
  const float* X = (const float*)d_in[0];
  const float* SV = (const float*)d_in[1];
  const float* DC = (const float*)d_in[2];
  const float* IC = (const float*)d_in[3];
  const float* gamma = (const float*)d_in[4];
  float* out = (float*)d_out;

  char* ws = (char*)d_ws;
  __bf16* Xb = (__bf16*)ws;                                   // 4 MB
  __bf16* SVb = (__bf16*)(ws + (size_t)NN * DD * 2);          // 8 MB
  float* x2 = (float*)(ws + (size_t)(NN + MM) * DD * 2);      // 16 KB
  float* sv2 = x2 + NN;                                       // 32 KB

  convert_norm_kernel<<<(NN + MM) / 4, 256, 0, stream>>>(X, SV, Xb, SVb, x2, sv2, out, IC);
  dim3 grid(NN / 128, MM / 128);
  rbf_gemm_kernel<<<grid, 256, 0, stream>>>((const bf16x8*)Xb, (const bf16x8*)SVb,
                                            x2, sv2, DC, gamma, out);
}